// Round 1
// baseline (105.329 us; speedup 1.0000x reference)
//
#include <hip/hip_runtime.h>
#include <math.h>

#define BSZ 128
#define T   512
#define E   128
#define H   128

// Workspace-free fused kernel.
//
// loss = sum_b sum_{m=3}^{len_b-1} [ LSE_{k=m}^{len_b-1} cterm[b,k] - cterm[b,m] ]
//        / sum_b (len_b - 3)
// where cterm[b,k] = dot(enc[b,k,:], fc_w[H:]).  LSTM hidden term and fc_b are
// separable in (j,k) and cancel exactly between lse and pos (see ref decomposition).
//
// Rationale for ws-free: the previous 2-kernel version used a 256 MiB workspace;
// rocprof showed two ~43 us fillBufferAligned dispatches (256 MiB poison each)
// dominating the 95.8 us measurement. This version touches only d_in/d_out.
//
// Per-block plan (grid = 128, one block per batch row b; 512 threads = 8 waves):
//   A. all 128 lengths computed redundantly per block (mask is 256 KB, L2-hot)
//      -> global denominator available without cross-block scratch
//   B. cterm[0..511] for own b into LDS: half-wave (32 lanes x float4) per row,
//      16 rows in flight per iteration, 32 iterations, fully coalesced (1 KB/wave)
//   C. suffix-LSE scan (row max -> exp -> Hillis-Steele suffix sum -> log)
//   D. atomicAdd(out, rs_b / denom); d_out zeroed by a 4-byte memset in launch.

__global__ __launch_bounds__(512) void dli_fused_kernel(
    const float* __restrict__ enc,    // [B*T, E]
    const int*   __restrict__ mask,   // [B*T]
    const float* __restrict__ fc_w,   // [H+E]
    float*       __restrict__ out)    // [1], pre-zeroed
{
    const int b    = blockIdx.x;
    const int t    = threadIdx.x;
    const int lane = t & 63;
    const int wid  = t >> 6;          // wave 0..7
    const int hw   = t >> 5;          // half-wave 0..15
    const int li   = t & 31;

    __shared__ float s_c[T];
    __shared__ float s_a[T];
    __shared__ float s_b[T];
    __shared__ int   s_len[BSZ];
    __shared__ float s_red[8];
    __shared__ float s_scalar[2];     // [0]=denom, [1]=Mrow

    // ---- Stage A: all lengths (wave w handles rows w*16 .. w*16+15) ----
    for (int j = 0; j < 16; ++j) {
        const int r = wid * 16 + j;
        const int* mrow = mask + r * T;
        int s = 0;
        #pragma unroll
        for (int k = 0; k < 8; ++k) s += mrow[lane + k * 64];
        #pragma unroll
        for (int off = 32; off >= 1; off >>= 1) s += __shfl_xor(s, off);
        if (lane == 0) s_len[r] = s;
    }
    __syncthreads();

    // denominator = sum_b max(len_b - 3, 0)
    {
        int v = (t < BSZ) ? (s_len[t] - 3) : 0;
        if (v < 0) v = 0;
        #pragma unroll
        for (int off = 32; off >= 1; off >>= 1) v += __shfl_xor(v, off);
        if (lane == 0) s_red[wid] = (float)v;
    }
    __syncthreads();
    if (t == 0) {
        float d = 0.0f;
        #pragma unroll
        for (int i = 0; i < 8; ++i) d += s_red[i];
        s_scalar[0] = d;
    }
    __syncthreads();
    const int   len   = s_len[b];
    const float denom = s_scalar[0];

    // ---- Stage B: cterm for own row b into s_c ----
    const float4 w4 = *reinterpret_cast<const float4*>(fc_w + H + 4 * li);
    const float* erow = enc + (long)b * T * E;
    #pragma unroll 4
    for (int it = 0; it < 32; ++it) {
        const int r = it * 16 + hw;
        const float4 v = *reinterpret_cast<const float4*>(erow + (long)r * E + 4 * li);
        float p = v.x * w4.x + v.y * w4.y + v.z * w4.z + v.w * w4.w;
        #pragma unroll
        for (int off = 16; off >= 1; off >>= 1) p += __shfl_xor(p, off);
        if (li == 0) s_c[r] = p;   // rows >= len hold garbage; never read below
    }
    __syncthreads();

    // ---- Stage C: row max over k in [3,len) ----
    float mval = (t >= 3 && t < len) ? s_c[t] : -INFINITY;
    #pragma unroll
    for (int off = 32; off >= 1; off >>= 1)
        mval = fmaxf(mval, __shfl_xor(mval, off));
    if (lane == 0) s_red[wid] = mval;
    __syncthreads();
    if (t == 0) {
        float m = s_red[0];
        #pragma unroll
        for (int i = 1; i < 8; ++i) m = fmaxf(m, s_red[i]);
        s_scalar[1] = m;
    }
    __syncthreads();
    const float Mrow = s_scalar[1];

    // exp terms, suffix inclusive sum (ping-pong Hillis-Steele, 9 steps)
    s_a[t] = (t >= 3 && t < len) ? expf(s_c[t] - Mrow) : 0.0f;
    __syncthreads();
    float* cur = s_a;
    float* nxt = s_b;
    #pragma unroll
    for (int d = 1; d < T; d <<= 1) {
        nxt[t] = cur[t] + ((t + d < T) ? cur[t + d] : 0.0f);
        float* tmp = cur; cur = nxt; nxt = tmp;
        __syncthreads();
    }

    float term = 0.0f;
    if (t >= 3 && t < len)
        term = Mrow + logf(cur[t]) - s_c[t];
    #pragma unroll
    for (int off = 32; off >= 1; off >>= 1)
        term += __shfl_xor(term, off);
    if (lane == 0) s_red[wid] = term;
    __syncthreads();

    if (t == 0) {
        float rs = 0.0f;
        #pragma unroll
        for (int i = 0; i < 8; ++i) rs += s_red[i];
        atomicAdd(out, rs / denom);   // 128 adds of ~loss/128 each; err ~1e-6
    }
}

extern "C" void kernel_launch(void* const* d_in, const int* in_sizes, int n_in,
                              void* d_out, int out_size, void* d_ws, size_t ws_size,
                              hipStream_t stream) {
    const float* enc  = (const float*)d_in[0];   // encoder_output [128,512,128] f32
    const int*   mask = (const int*)d_in[1];     // mask [128,512] i32
    const float* fc_w = (const float*)d_in[6];   // fc_w [1,256] f32
    // d_in[2..5] (LSTM weights) and d_in[7] (fc_b) cancel analytically.
    // d_ws intentionally unused (theory: 256 MiB ws poison fills dominate timing).

    hipMemsetAsync(d_out, 0, 4, stream);         // zero the scalar accumulator

    dli_fused_kernel<<<BSZ, T, 0, stream>>>(enc, mask, fc_w, (float*)d_out);
}

// Round 2
// 95.998 us; speedup vs baseline: 1.0972x; 1.0972x over previous
//
#include <hip/hip_runtime.h>
#include <math.h>

#define BSZ 128
#define T   512
#define E   128
#define H   128

// Workspace layout (ws is POISONED by the harness every iteration — two ~43 µs
// 256 MiB fills that dominate dur_us and are unconditional; round-1 proved they
// persist even with ws unused):
//   [0]    double accum[2]  {loss_sum, pair_count}   (zeroed by dot kernel blk 0)
//   [16]   int    scan_done                          (zeroed by dot kernel blk 0)
//   [1024] float  cterm[B*T]   (only entries with mask=1 && t>=3 are written/read)
//
// loss = sum_b sum_{m=3}^{len_b-1} [ LSE_{k=m}^{len_b-1} cterm[b,k] - cterm[b,m] ]
//        / sum_b (len_b - 3)
// where cterm[b,k] = dot(enc[b,k,:], fc_w[H:]).  The LSTM hidden term and fc_b
// are separable in (j,k) and cancel exactly between lse and pos.
//
// vs round-0 best (95.76 µs): dropped the 32-B memset dispatch (zeroing folded
// into dot kernel block 0), skip t<3 rows, scan kernel 13 -> 6 barriers.

// ---------------- Phase 1: cterm = enc . w_e ----------------
// Half-wave (32 lanes x float4) per row; 8 rows/block; 8192 blocks.
__global__ __launch_bounds__(256) void dli_dot_kernel(
    const float* __restrict__ enc,    // [B*T, E]
    const int*   __restrict__ mask,   // [B*T]
    const float* __restrict__ fc_w,   // [H+E]
    float*       __restrict__ cterm,  // ws scratch [B*T]
    double*      __restrict__ accum,
    int*         __restrict__ scan_done)
{
    const int t = threadIdx.x;
    if (blockIdx.x == 0 && t == 0) {   // replaces the hipMemsetAsync dispatch;
        accum[0] = 0.0;                // visible to scan kernel via stream order
        accum[1] = 0.0;                // + kernel-completion release
        *scan_done = 0;
    }
    const int wid  = t >> 6;
    const int lane = t & 63;
    const int sub  = lane >> 5;
    const int li   = lane & 31;
    const long row = (long)blockIdx.x * 8 + wid * 2 + sub;

    if ((row & (T - 1)) < 3) return;   // k<3 never read downstream
    if (mask[row] == 0) return;        // prefix mask: k>=len never read downstream

    const float4 w4 = *reinterpret_cast<const float4*>(fc_w + H + 4 * li);
    const float4 v  = *reinterpret_cast<const float4*>(enc + row * E + 4 * li);
    float p = v.x * w4.x + v.y * w4.y + v.z * w4.z + v.w * w4.w;
    #pragma unroll
    for (int off = 16; off >= 1; off >>= 1)
        p += __shfl_xor(p, off);
    if (li == 0) cterm[row] = p;
}

// ---------------- Phase 2: suffix-LSE per row + masked mean + finalize ----------------
// 6 barriers total (was 13): ballot length count, shuffle max, wave-segmented
// suffix sum (6 shfl_down steps, no barrier) + one cross-wave combine.
__global__ __launch_bounds__(T) void dli_scan_kernel(
    const float* __restrict__ cterm,
    const int*   __restrict__ mask,
    double*      __restrict__ accum,
    int*         __restrict__ scan_done,
    float*       __restrict__ out)
{
    const int b    = blockIdx.x;
    const int t    = threadIdx.x;
    const int lane = t & 63;
    const int wid  = t >> 6;

    __shared__ float s_c[T];
    __shared__ float s_red[8];
    __shared__ int   s_lw[8];
    __shared__ float s_M;

    const int mv = mask[b * T + t];
    unsigned long long bal = __ballot(mv != 0);
    if (lane == 0) s_lw[wid] = __popcll(bal);
    s_c[t] = mv ? cterm[b * T + t] : 0.0f;   // masked entries unwritten (poison)
    __syncthreads();                                   // B1

    int len = 0;
    #pragma unroll
    for (int i = 0; i < 8; ++i) len += s_lw[i];        // len >= 4 guaranteed

    const bool act = (t >= 3 && t < len);

    // row max over k in [3,len)
    float mval = act ? s_c[t] : -INFINITY;
    #pragma unroll
    for (int off = 32; off >= 1; off >>= 1)
        mval = fmaxf(mval, __shfl_xor(mval, off));
    if (lane == 0) s_red[wid] = mval;
    __syncthreads();                                   // B2
    if (t == 0) {
        float m = s_red[0];
        #pragma unroll
        for (int i = 1; i < 8; ++i) m = fmaxf(m, s_red[i]);
        s_M = m;
    }
    __syncthreads();                                   // B3
    const float Mrow = s_M;

    // exp terms; inclusive suffix sum: wave-segmented shfl_down, then add
    // totals of later waves.
    float x = act ? expf(s_c[t] - Mrow) : 0.0f;
    #pragma unroll
    for (int off = 1; off < 64; off <<= 1) {
        float y = __shfl_down(x, off);
        if (lane + off < 64) x += y;
    }
    if (lane == 0) s_red[wid] = x;                     // wave suffix totals
    __syncthreads();                                   // B4
    float tail = 0.0f;
    for (int w = wid + 1; w < 8; ++w) tail += s_red[w];
    float term = act ? (Mrow + logf(x + tail) - s_c[t]) : 0.0f;
    __syncthreads();                                   // B5 (s_red reuse)

    #pragma unroll
    for (int off = 32; off >= 1; off >>= 1)
        term += __shfl_xor(term, off);
    if (lane == 0) s_red[wid] = term;
    __syncthreads();                                   // B6

    if (t == 0) {
        float rs = 0.0f;
        #pragma unroll
        for (int i = 0; i < 8; ++i) rs += s_red[i];
        int cnt = len - 3; if (cnt < 0) cnt = 0;
        atomicAdd(&accum[0], (double)rs);
        atomicAdd(&accum[1], (double)cnt);
        __threadfence();                     // order accum adds before arrival
        int old = atomicAdd(scan_done, 1);
        if (old == BSZ - 1) {                // last block finalizes
            __threadfence();                 // acquire others' accum adds
            double a0 = atomicAdd(&accum[0], 0.0);
            double a1 = atomicAdd(&accum[1], 0.0);
            out[0] = (float)(a0 / a1);
        }
    }
}

extern "C" void kernel_launch(void* const* d_in, const int* in_sizes, int n_in,
                              void* d_out, int out_size, void* d_ws, size_t ws_size,
                              hipStream_t stream) {
    const float* enc  = (const float*)d_in[0];   // encoder_output [128,512,128] f32
    const int*   mask = (const int*)d_in[1];     // mask [128,512] i32
    const float* fc_w = (const float*)d_in[6];   // fc_w [1,256] f32
    // d_in[2..5] (LSTM weights) and d_in[7] (fc_b) cancel analytically.

    double* accum     = (double*)d_ws;
    int*    scan_done = (int*)((char*)d_ws + 16);
    float*  cterm     = (float*)((char*)d_ws + 1024);

    dli_dot_kernel<<<(BSZ * T) / 8, 256, 0, stream>>>(enc, mask, fc_w, cterm,
                                                      accum, scan_done);
    dli_scan_kernel<<<BSZ, T, 0, stream>>>(cterm, mask, accum, scan_done,
                                           (float*)d_out);
}

// Round 3
// 94.286 us; speedup vs baseline: 1.1171x; 1.0182x over previous
//
#include <hip/hip_runtime.h>
#include <math.h>

#define BSZ 128
#define T   512
#define E   128
#define H   128

// Fused single-kernel version.
//
// loss = sum_b sum_{m=3}^{len_b-1} [ LSE_{k=m}^{len_b-1} cterm[b,k] - cterm[b,m] ]
//        / sum_b (len_b - 3)
// where cterm[b,k] = dot(enc[b,k,:], fc_w[H:]).  LSTM hidden term and fc_b are
// separable in (j,k) and cancel exactly between lse and pos.
//
// Measured context: harness re-poisons the 256 MiB workspace with two ~43 µs
// 256 MiB fills every iteration (unconditional — proven in round 1). Residual
// above the fills is ~9.6 µs of our kernels. This version fuses dot+scan into
// one kernel to kill the cterm ws round-trip and the second launch:
//   - block b reads ONLY its own mask row (2 KB) and enc rows [3, len_b) —
//     ~17 MB total (vs round-1 fused's 33.5 MB enc + 32 MB mask re-reads).
//   - 1024 thr/block = 32 half-waves; clamped row index keeps the dot loop
//     uniform so unroll-4 keeps 4 float4 loads/half-wave in flight.
//   - dot result -> LDS s_c directly; suffix-LSE scan in-block.
//   - global mean via accum[2] + scan_done last-block finalize (ws, zeroed by
//     a 32-B memset dispatch — measured free in rounds 0->2).

__global__ __launch_bounds__(1024) void dli_fused_kernel(
    const float* __restrict__ enc,    // [B*T, E]
    const int*   __restrict__ mask,   // [B*T]
    const float* __restrict__ fc_w,   // [H+E]
    double*      __restrict__ accum,  // ws[0..1]: {loss_sum, pair_count}
    int*         __restrict__ scan_done,
    float*       __restrict__ out)
{
    const int b    = blockIdx.x;
    const int t    = threadIdx.x;
    const int lane = t & 63;
    const int wid  = t >> 6;          // wave 0..15
    const int hw   = t >> 5;          // half-wave 0..31
    const int li   = t & 31;

    __shared__ float s_c[T];
    __shared__ float s_red[8];
    __shared__ int   s_lw[8];
    __shared__ float s_M;

    // ---- length of own row from mask ballot (first 8 waves) ----
    if (t < T) {
        const int mv = mask[b * T + t];
        unsigned long long bal = __ballot(mv != 0);
        if (lane == 0) s_lw[wid] = __popcll(bal);
    }
    __syncthreads();                                   // B1
    int len = 0;
    #pragma unroll
    for (int i = 0; i < 8; ++i) len += s_lw[i];        // len in [4, 512]

    // ---- dot phase: s_c[r] = dot(enc[b,r,:], w_e) for r in [3, len) ----
    const float4 w4 = *reinterpret_cast<const float4*>(fc_w + H + 4 * li);
    const float* erow = enc + (long)b * T * E;
    #pragma unroll 4
    for (int r0 = 3; r0 < len; r0 += 32) {
        int r_raw = r0 + hw;
        int r = r_raw < len ? r_raw : len - 1;         // clamp: uniform trip count
        const float4 v = *reinterpret_cast<const float4*>(erow + (long)r * E + 4 * li);
        float p = v.x * w4.x + v.y * w4.y + v.z * w4.z + v.w * w4.w;
        #pragma unroll
        for (int off = 16; off >= 1; off >>= 1)
            p += __shfl_xor(p, off);
        if (li == 0 && r_raw < len) s_c[r_raw] = p;
    }
    __syncthreads();                                   // B2

    // ---- scan phase (threads < T): suffix-LSE over k in [3,len) ----
    const bool sth = (t < T);
    const bool act = sth && (t >= 3 && t < len);

    float mval = act ? s_c[t] : -INFINITY;
    if (sth) {
        #pragma unroll
        for (int off = 32; off >= 1; off >>= 1)
            mval = fmaxf(mval, __shfl_xor(mval, off));
        if (lane == 0) s_red[wid] = mval;
    }
    __syncthreads();                                   // B3
    if (t == 0) {
        float m = s_red[0];
        #pragma unroll
        for (int i = 1; i < 8; ++i) m = fmaxf(m, s_red[i]);
        s_M = m;
    }
    __syncthreads();                                   // B4
    const float Mrow = s_M;

    // exp terms; inclusive suffix sum: wave-segmented shfl_down + cross-wave tail
    float x = act ? expf(s_c[t] - Mrow) : 0.0f;
    if (sth) {
        #pragma unroll
        for (int off = 1; off < 64; off <<= 1) {
            float y = __shfl_down(x, off);
            if (lane + off < 64) x += y;
        }
        if (lane == 0) s_red[wid] = x;                 // wave suffix totals
    }
    __syncthreads();                                   // B5
    float term = 0.0f;
    if (act) {
        float tail = 0.0f;
        for (int w = wid + 1; w < 8; ++w) tail += s_red[w];
        term = Mrow + logf(x + tail) - s_c[t];
    }
    __syncthreads();                                   // B6 (s_red reuse)

    if (sth) {
        #pragma unroll
        for (int off = 32; off >= 1; off >>= 1)
            term += __shfl_xor(term, off);
        if (lane == 0) s_red[wid] = term;
    }
    __syncthreads();                                   // B7

    if (t == 0) {
        float rs = 0.0f;
        #pragma unroll
        for (int i = 0; i < 8; ++i) rs += s_red[i];
        int cnt = len - 3;
        atomicAdd(&accum[0], (double)rs);
        atomicAdd(&accum[1], (double)cnt);
        __threadfence();                     // order accum adds before arrival
        int old = atomicAdd(scan_done, 1);
        if (old == BSZ - 1) {                // last block finalizes
            __threadfence();                 // acquire others' accum adds
            double a0 = atomicAdd(&accum[0], 0.0);
            double a1 = atomicAdd(&accum[1], 0.0);
            out[0] = (float)(a0 / a1);
        }
    }
}

extern "C" void kernel_launch(void* const* d_in, const int* in_sizes, int n_in,
                              void* d_out, int out_size, void* d_ws, size_t ws_size,
                              hipStream_t stream) {
    const float* enc  = (const float*)d_in[0];   // encoder_output [128,512,128] f32
    const int*   mask = (const int*)d_in[1];     // mask [128,512] i32
    const float* fc_w = (const float*)d_in[6];   // fc_w [1,256] f32
    // d_in[2..5] (LSTM weights) and d_in[7] (fc_b) cancel analytically.

    double* accum     = (double*)d_ws;
    int*    scan_done = (int*)((char*)d_ws + 16);

    hipMemsetAsync(d_ws, 0, 32, stream);         // accum + scan_done

    dli_fused_kernel<<<BSZ, 1024, 0, stream>>>(enc, mask, fc_w, accum, scan_done,
                                               (float*)d_out);
}